// Round 16
// baseline (328.371 us; speedup 1.0000x reference)
//
#include <hip/hip_runtime.h>

#define T_ 2048
#define D_ 4096
#define H_ 32
#define G_ 8
#define HD_ 128

typedef float f32x4 __attribute__((ext_vector_type(4)));
typedef float f32x16 __attribute__((ext_vector_type(16)));
typedef __bf16 bf16x8 __attribute__((ext_vector_type(8)));
typedef unsigned short u16x8 __attribute__((ext_vector_type(8)));
typedef unsigned short u16x4 __attribute__((ext_vector_type(4)));

__device__ __forceinline__ unsigned short f2bf(float f) {
  unsigned u = __builtin_bit_cast(unsigned, f);
  u += 0x7FFFu + ((u >> 16) & 1u);
  return (unsigned short)(u >> 16);
}
__device__ __forceinline__ float bf2f(unsigned short h) {
  return __builtin_bit_cast(float, (unsigned)h << 16);
}

__device__ __forceinline__ void gload_lds16(const unsigned short* g, unsigned short* l) {
  __builtin_amdgcn_global_load_lds((const __attribute__((address_space(1))) void*)g,
                                   (__attribute__((address_space(3))) void*)l, 16, 0, 0);
}

// ---------------- elementwise f32 -> bf16 ----------------
__global__ __launch_bounds__(256) void convert_bf16(const float* __restrict__ in,
                                                    unsigned short* __restrict__ out) {
  const size_t i = ((size_t)blockIdx.x * 256 + threadIdx.x) * 8;
  float4 a = *(const float4*)(in + i);
  float4 b = *(const float4*)(in + i + 4);
  u16x8 o;
  o[0] = f2bf(a.x); o[1] = f2bf(a.y); o[2] = f2bf(a.z); o[3] = f2bf(a.w);
  o[4] = f2bf(b.x); o[5] = f2bf(b.y); o[6] = f2bf(b.z); o[7] = f2bf(b.w);
  *(u16x8*)(out + i) = o;
}

// ---------------- single-W transpose + convert: W (R,C) f32 -> Wt (C,R) bf16 ----------------
__global__ __launch_bounds__(256) void transpose_convert(const float* __restrict__ Wm,
                                                         unsigned short* __restrict__ Wt,
                                                         int R, int C) {
  __shared__ float tile[64][65];
  const int r0 = blockIdx.x * 64, c0 = blockIdx.y * 64;
  const int lr4 = threadIdx.x >> 6, lc = threadIdx.x & 63;
#pragma unroll
  for (int i = 0; i < 16; ++i) {
    int r = i * 4 + lr4;
    tile[r][lc] = Wm[(size_t)(r0 + r) * C + c0 + lc];
  }
  __syncthreads();
#pragma unroll
  for (int i = 0; i < 16; ++i) {
    int r = i * 4 + lr4;
    Wt[(size_t)(c0 + r) * R + r0 + lc] = f2bf(tile[lc][r]);
  }
}

// ---------------- merged Wq/Wk/Wv transpose: out rows 0..6143 of WqkvT ----------------
__global__ __launch_bounds__(256) void transpose_convert_qkv(const float* __restrict__ Wq,
                                                             const float* __restrict__ Wk,
                                                             const float* __restrict__ Wv,
                                                             unsigned short* __restrict__ Wt) {
  __shared__ float tile[64][65];
  const int r0 = blockIdx.x * 64;
  const int cg = blockIdx.y * 64;  // output row base = concat source-col base
  const float* Wm;
  int C, c0;
  if (cg < 4096)      { Wm = Wq; C = 4096; c0 = cg; }
  else if (cg < 5120) { Wm = Wk; C = 1024; c0 = cg - 4096; }
  else                { Wm = Wv; C = 1024; c0 = cg - 5120; }
  const int lr4 = threadIdx.x >> 6, lc = threadIdx.x & 63;
#pragma unroll
  for (int i = 0; i < 16; ++i) {
    int r = i * 4 + lr4;
    tile[r][lc] = Wm[(size_t)(r0 + r) * C + c0 + lc];
  }
  __syncthreads();
#pragma unroll
  for (int i = 0; i < 16; ++i) {
    int r = i * 4 + lr4;
    Wt[(size_t)(cg + r) * 4096 + r0 + lc] = f2bf(tile[lc][r]);
  }
}

// ---------------- transpose v: (T, stride) bf16 cols -> (G, HD, T) bf16 ----------------
__global__ __launch_bounds__(256) void transpose_v(const unsigned short* __restrict__ v,
                                                   unsigned short* __restrict__ vt, int stride) {
  __shared__ unsigned short tile[64][65];
  const int t0 = blockIdx.x * 64, d0 = blockIdx.y * 64, g = blockIdx.z;
  const int lr4 = threadIdx.x >> 6, lc = threadIdx.x & 63;
#pragma unroll
  for (int i = 0; i < 16; ++i) {
    int r = i * 4 + lr4;
    tile[r][lc] = v[(size_t)(t0 + r) * stride + g * HD_ + d0 + lc];
  }
  __syncthreads();
#pragma unroll
  for (int i = 0; i < 16; ++i) {
    int r = i * 4 + lr4;
    vt[((size_t)g * HD_ + d0 + r) * T_ + t0 + lc] = tile[lc][r];
  }
}

// ---------------- merged RMSNorm + RoPE for q AND k ----------------
__global__ __launch_bounds__(256) void norm_rope2(const unsigned short* __restrict__ qkv,
                                                  unsigned short* __restrict__ qout,
                                                  unsigned short* __restrict__ kout,
                                                  const float* __restrict__ qw,
                                                  const float* __restrict__ kw,
                                                  const float* __restrict__ cs,
                                                  const float* __restrict__ sn) {
  int bid = blockIdx.x;
  const unsigned short* raw;
  unsigned short* outp;
  const float* w;
  int NH;
  if (bid < 16384) { raw = qkv;        outp = qout; w = qw; NH = 32; }
  else             { raw = qkv + 4096; outp = kout; w = kw; NH = 8; bid -= 16384; }
  const int row = bid * 4 + (threadIdx.x >> 6);
  const int lane = threadIdx.x & 63;
  const int t = row / NH, h = row - t * NH;
  const unsigned short* src = raw + (size_t)t * 6144 + h * HD_;
  float u1 = bf2f(src[lane]);
  float u2 = bf2f(src[lane + 64]);
  float ss = u1 * u1 + u2 * u2;
#pragma unroll
  for (int m = 1; m < 64; m <<= 1) ss += __shfl_xor(ss, m);
  float rr = rsqrtf(ss * (1.f / 128.f) + 1e-6f);
  float c = cs[(size_t)t * HD_ + lane];  // cos[d] == cos[d+64] (concat(freqs,freqs))
  float s = sn[(size_t)t * HD_ + lane];
  float a = u1 * rr * w[lane];
  float b = u2 * rr * w[lane + 64];
  unsigned short* dst = outp + ((size_t)h * T_ + t) * HD_;
  dst[lane]      = f2bf(a * c - b * s);
  dst[lane + 64] = f2bf(b * c + a * s);
}

// ---------------- 128 x (64*NT) GEMM, 4 waves (2x2), 32x32x16 MFMA, 2 blocks/CU ----------------
// Same merged-region schedule / staging / slot-ring / vmcnt(4) invariant as R15's gemm4
// (B = NT stage-units -> 2*NT gload issues, A = 4 issues per step; end-of-step vmcnt(4)
// retires A(t+1)+B(t+1), keeps A(t+2) in flight). Only the fragment geometry changes:
// wave tile 64 x (32*NT) as 2 x NT tiles of 32x32; K-step 64 = 4 sub-K of 16.
// Operand frags (guide-verified): row/col = lane&31, k = (lane>>5)*8 + j (one b128 each).
// C/D layout (m74/m101): col = lane&31, row = (reg&3) + 8*(reg>>2) + 4*(lane>>5).
// A reads 8, B reads 4*NT per wave-step; MFMA 8*NT per wave-step (vs 16*NT at 16x16).
template <int NT, int OUTF32>
__global__ __launch_bounds__(256, 2) void gemm5(const unsigned short* __restrict__ A,
                                                const unsigned short* __restrict__ Bt,
                                                void* __restrict__ Cv, int M, int N,
                                                int K, int LDA) {
  constexpr int BN = 64 * NT;         // 192 (NT=3) or 128 (NT=2)
  constexpr int ABUF = 8192;          // ushorts per A dbuf (128x64)
  constexpr int BBUF = BN * 64;       // ushorts per B dbuf
  __shared__ __align__(16) unsigned short lds[2 * ABUF + 2 * BBUF];
  const int tid = threadIdx.x;
  const int wid = tid >> 6, lane = tid & 63;
  const int lr32 = lane & 31, lhi32 = lane >> 5;
  const int wr = wid >> 1, wcn = wid & 1;

  // XCD-aware swizzle (nwg = 512, bijective); gridDim.x == 16 row-blocks
  int flat = blockIdx.y * gridDim.x + blockIdx.x;
  int nwg = gridDim.x * gridDim.y;
  int swz = (flat & 7) * (nwg >> 3) + (flat >> 3);
  const int brow = (swz & 15) * 128;
  const int bcol = (swz >> 4) * BN;

  const int nt = K >> 6;

  f32x16 acc[2][NT];
#pragma unroll
  for (int a = 0; a < 2; ++a)
#pragma unroll
    for (int c = 0; c < NT; ++c)
#pragma unroll
      for (int r = 0; r < 16; ++r) acc[a][c][r] = 0.f;

  // staging: unit = 64 rows x 64 cols bf16 (8 KB) = 256 thr x 2 x 16 B  (R15 verbatim)
  const int t8 = tid >> 3;                        // row within 32-row half-unit
  const int srcCol = ((tid & 7) ^ (t8 & 7)) * 8;  // inverse-swizzled source col
  auto stageA = [&](int d, int u, int ktp) {
#pragma unroll
    for (int l = 0; l < 2; ++l)
      gload_lds16(A + (size_t)(brow + u * 64 + l * 32 + t8) * LDA + ktp * 64 + srcCol,
                  &lds[d * ABUF + u * 4096 + l * 2048 + tid * 8]);
  };
  auto stageB = [&](int d, int v, int ktp) {
#pragma unroll
    for (int l = 0; l < 2; ++l)
      gload_lds16(Bt + (size_t)(bcol + v * 64 + l * 32 + t8) * LDA + ktp * 64 + srcCol,
                  &lds[2 * ABUF + d * BBUF + v * 4096 + l * 2048 + tid * 8]);
  };

  bf16x8 af[2][4], bf[NT][4];
  auto readA = [&](int d) {
#pragma unroll
    for (int ar = 0; ar < 2; ++ar) {
      int row = wr * 64 + ar * 32 + lr32;
      int base = d * ABUF + row * 64;
      int sw = (row & 7) << 3;
#pragma unroll
      for (int sk = 0; sk < 4; ++sk)
        af[ar][sk] = *(const bf16x8*)&lds[base + ((sk * 16 + lhi32 * 8) ^ sw)];
    }
  };
  auto readB = [&](int d) {
#pragma unroll
    for (int bc = 0; bc < NT; ++bc) {
      int row = wcn * (32 * NT) + bc * 32 + lr32;
      int base = 2 * ABUF + d * BBUF + row * 64;
      int sw = (row & 7) << 3;
#pragma unroll
      for (int sk = 0; sk < 4; ++sk)
        bf[bc][sk] = *(const bf16x8*)&lds[base + ((sk * 16 + lhi32 * 8) ^ sw)];
    }
  };

  // prologue: step0 full -> d0; A(step1) -> d1 (nt >= 2 here)
  stageA(0, 0, 0); stageA(0, 1, 0);
#pragma unroll
  for (int v = 0; v < NT; ++v) stageB(0, v, 0);
  stageA(1, 0, 1); stageA(1, 1, 1);
  asm volatile("s_waitcnt vmcnt(4)" ::: "memory");
  __builtin_amdgcn_s_barrier();

  for (int t = 0; t < nt; ++t) {
    const int d = t & 1, dn = d ^ 1;
    // all ds_reads first (A both halves + B, independent regs)
    readA(d);
    readB(d);
    // stage next-step B into the other dbuf
    if (t + 1 < nt) {
#pragma unroll
      for (int v = 0; v < NT; ++v) stageB(dn, v, t + 1);
    }
    // MFMA ar=0: compiler interleaves the pending ds_reads under these
#pragma unroll
    for (int sk = 0; sk < 4; ++sk)
#pragma unroll
      for (int bc = 0; bc < NT; ++bc)
        acc[0][bc] = __builtin_amdgcn_mfma_f32_32x32x16_bf16(af[0][sk], bf[bc][sk],
                                                             acc[0][bc], 0, 0, 0);
    // all waves' A-reads issued -> safe to overwrite A slots of dbuf d
    __builtin_amdgcn_s_barrier();
    if (t + 2 < nt) { stageA(d, 0, t + 2); stageA(d, 1, t + 2); }
    // MFMA ar=1 covers the stageA DMA latency
#pragma unroll
    for (int sk = 0; sk < 4; ++sk)
#pragma unroll
      for (int bc = 0; bc < NT; ++bc)
        acc[1][bc] = __builtin_amdgcn_mfma_f32_32x32x16_bf16(af[1][sk], bf[bc][sk],
                                                             acc[1][bc], 0, 0, 0);
    if (t < nt - 2) asm volatile("s_waitcnt vmcnt(4)" ::: "memory");
    else if (t == nt - 2) asm volatile("s_waitcnt vmcnt(0)" ::: "memory");
    __builtin_amdgcn_s_barrier();
  }

  // epilogue: C/D 32x32 layout col=lane&31, row=(reg&3)+8*(reg>>2)+4*(lane>>5)
#pragma unroll
  for (int ar = 0; ar < 2; ++ar)
#pragma unroll
    for (int bc = 0; bc < NT; ++bc) {
      int col = bcol + wcn * (32 * NT) + bc * 32 + lr32;
#pragma unroll
      for (int reg = 0; reg < 16; ++reg) {
        int row = brow + wr * 64 + ar * 32 + (reg & 3) + 8 * (reg >> 2) + 4 * lhi32;
        if (OUTF32)
          ((float*)Cv)[(size_t)row * N + col] = acc[ar][bc][reg];
        else
          ((unsigned short*)Cv)[(size_t)row * N + col] = f2bf(acc[ar][bc][reg]);
      }
    }
}

// ---------------- causal flash attention: 2 heads/block, PAIRED q-chunks (R9 verbatim) ----------------
__global__ __launch_bounds__(512) void flash_attn(const unsigned short* __restrict__ q,
                                                  const unsigned short* __restrict__ k,
                                                  const unsigned short* __restrict__ vt,
                                                  unsigned short* __restrict__ attnb) {
  const int pairIdx = blockIdx.y;
  const int g = pairIdx >> 1;  // GS = 4, 2 heads/block
  const int qcp = blockIdx.x;  // pair slot: chunks {qcp, 31-qcp}
  const int tid = threadIdx.x;
  const int wid = tid >> 6;
  const int lane = tid & 63;
  const int lr = lane & 15, lhi = lane >> 4;
  const int h = pairIdx * 2 + (wid >> 2);

  __shared__ __align__(16) unsigned short Ks[2][64 * HD_];
  __shared__ __align__(16) unsigned short Vs[2][HD_ * 64];
  __shared__ __align__(16) unsigned short p_lds_all[8][16 * 64];
  unsigned short* p_lds = p_lds_all[wid];

  const unsigned short* kg = k + (size_t)g * T_ * HD_;
  const unsigned short* vg = vt + (size_t)g * HD_ * T_;

  int ko[2], vo[2];
#pragma unroll
  for (int p = 0; p < 2; ++p) {
    int ob = (p * 512 + tid) * 16;
    int krow = ob >> 8, kb = ob & 255;
    ko[p] = krow * HD_ + ((kb ^ ((krow & 7) << 4)) >> 1);
    int vrow = ob >> 7, vb2 = ob & 127;
    vo[p] = vrow * T_ + ((vb2 ^ ((vrow & 7) << 4)) >> 1);
  }
  const int lbase = wid * 512;

  const int sx = (lr & 7) << 4;
  const float scale2 = 0.08838834764831845f * 1.4426950408889634f;

  for (int pass = 0; pass < 2; ++pass) {
    const int qc = pass ? (31 - qcp) : qcp;
    const int q0 = qc * 64 + (wid & 3) * 16;

    bf16x8 qf[4];
    {
      const unsigned short* qrow = q + ((size_t)h * T_ + q0 + lr) * HD_ + lhi * 8;
#pragma unroll
      for (int c = 0; c < 4; ++c) qf[c] = *(const bf16x8*)(qrow + c * 32);
    }
    f32x4 accO[8];
#pragma unroll
    for (int i = 0; i < 8; ++i) accO[i] = (f32x4){0.f, 0.f, 0.f, 0.f};
    float mrow = -3e38f;
    float lrow = 0.f;

    const int ntile = qc + 1;

    // prologue: stage tile 0 into buffer 0 (previous pass fully drained)
#pragma unroll
    for (int p = 0; p < 2; ++p) {
      gload_lds16(kg + ko[p], &Ks[0][p * 4096 + lbase]);
      gload_lds16(vg + vo[p], &Vs[0][p * 4096 + lbase]);
    }
    __syncthreads();

    for (int kt = 0; kt < ntile; ++kt) {
      const int b = kt & 1;
      const int kv0 = kt << 6;
      if (kt + 1 < ntile) {
        const size_t kofs = (size_t)(kv0 + 64) * HD_;
#pragma unroll
        for (int p = 0; p < 2; ++p) {
          gload_lds16(kg + kofs + ko[p], &Ks[b ^ 1][p * 4096 + lbase]);
          gload_lds16(vg + (kv0 + 64) + vo[p], &Vs[b ^ 1][p * 4096 + lbase]);
        }
      }
      f32x4 st[4];
      __builtin_amdgcn_s_setprio(1);
#pragma unroll
      for (int j = 0; j < 4; ++j) {
        st[j] = (f32x4){0.f, 0.f, 0.f, 0.f};
        const int krow = j * 16 + lr;
#pragma unroll
        for (int c = 0; c < 4; ++c) {
          bf16x8 kf = *(const bf16x8*)&Ks[b][krow * HD_ + (((c * 64 + lhi * 16) ^ sx) >> 1)];
          st[j] = __builtin_amdgcn_mfma_f32_16x16x32_bf16(kf, qf[c], st[j], 0, 0, 0);
        }
      }
      __builtin_amdgcn_s_setprio(0);
      if (kt == ntile - 1) {
#pragma unroll
        for (int j = 0; j < 4; ++j)
#pragma unroll
          for (int r = 0; r < 4; ++r)
            st[j][r] = (kv0 + j * 16 + lhi * 4 + r <= q0 + lr) ? st[j][r] * scale2 : -3e38f;
      } else {
#pragma unroll
        for (int j = 0; j < 4; ++j)
#pragma unroll
          for (int r = 0; r < 4; ++r) st[j][r] *= scale2;
      }
      float pm = st[0][0];
#pragma unroll
      for (int j = 0; j < 4; ++j)
#pragma unroll
        for (int r = 0; r < 4; ++r) pm = fmaxf(pm, st[j][r]);
      pm = fmaxf(pm, __shfl_xor(pm, 16));
      pm = fmaxf(pm, __shfl_xor(pm, 32));
      if (!__all(pm - mrow <= 8.f)) {
        float mnew = fmaxf(mrow, pm);
        float al = __builtin_amdgcn_exp2f(mrow - mnew);
        mrow = mnew;
        lrow *= al;
        float a0 = __shfl(al, lhi * 4 + 0);
        float a1 = __shfl(al, lhi * 4 + 1);
        float a2 = __shfl(al, lhi * 4 + 2);
        float a3 = __shfl(al, lhi * 4 + 3);
#pragma unroll
        for (int dt = 0; dt < 8; ++dt) {
          accO[dt][0] *= a0; accO[dt][1] *= a1; accO[dt][2] *= a2; accO[dt][3] *= a3;
        }
      }
      float ps = 0.f;
#pragma unroll
      for (int j = 0; j < 4; ++j)
#pragma unroll
        for (int r = 0; r < 4; ++r) {
          float e = __builtin_amdgcn_exp2f(st[j][r] - mrow);
          st[j][r] = e;
          ps += e;
        }
      ps += __shfl_xor(ps, 16);
      ps += __shfl_xor(ps, 32);
      lrow += ps;
#pragma unroll
      for (int j = 0; j < 4; ++j) {
        u16x4 pw;
        pw[0] = f2bf(st[j][0]); pw[1] = f2bf(st[j][1]);
        pw[2] = f2bf(st[j][2]); pw[3] = f2bf(st[j][3]);
        *(u16x4*)&p_lds[lr * 64 + (((j * 32 + lhi * 8) ^ sx) >> 1)] = pw;
      }
      bf16x8 pa0 = *(const bf16x8*)&p_lds[lr * 64 + (((lhi * 16) ^ sx) >> 1)];
      bf16x8 pa1 = *(const bf16x8*)&p_lds[lr * 64 + (((64 + lhi * 16) ^ sx) >> 1)];
      __builtin_amdgcn_s_setprio(1);
#pragma unroll
      for (int dt = 0; dt < 8; ++dt) {
        const int vrow = dt * 16 + lr;
        bf16x8 vf0 = *(const bf16x8*)&Vs[b][vrow * 64 + (((lhi * 16) ^ sx) >> 1)];
        bf16x8 vf1 = *(const bf16x8*)&Vs[b][vrow * 64 + (((64 + lhi * 16) ^ sx) >> 1)];
        accO[dt] = __builtin_amdgcn_mfma_f32_16x16x32_bf16(pa0, vf0, accO[dt], 0, 0, 0);
        accO[dt] = __builtin_amdgcn_mfma_f32_16x16x32_bf16(pa1, vf1, accO[dt], 0, 0, 0);
      }
      __builtin_amdgcn_s_setprio(0);
      __syncthreads();
    }
    float rinv = 1.f / lrow;
    float i0 = __shfl(rinv, lhi * 4 + 0);
    float i1 = __shfl(rinv, lhi * 4 + 1);
    float i2 = __shfl(rinv, lhi * 4 + 2);
    float i3 = __shfl(rinv, lhi * 4 + 3);
    float iv[4] = {i0, i1, i2, i3};
#pragma unroll
    for (int r = 0; r < 4; ++r) {
      size_t rowoff = (size_t)(q0 + lhi * 4 + r) * (H_ * HD_) + h * HD_;
#pragma unroll
      for (int dt = 0; dt < 8; ++dt) attnb[rowoff + dt * 16 + lr] = f2bf(accO[dt][r] * iv[r]);
    }
  }
}

extern "C" void kernel_launch(void* const* d_in, const int* in_sizes, int n_in,
                              void* d_out, int out_size, void* d_ws, size_t ws_size,
                              hipStream_t stream) {
  const float* x = (const float*)d_in[0];
  // d_in[1] = mask (bool) — causal mask computed analytically, unused
  const float* cosT = (const float*)d_in[2];
  const float* sinT = (const float*)d_in[3];
  const float* Wq = (const float*)d_in[4];
  const float* Wk = (const float*)d_in[5];
  const float* Wv = (const float*)d_in[6];
  const float* Wo = (const float*)d_in[7];
  const float* qn = (const float*)d_in[8];
  const float* kn = (const float*)d_in[9];

  unsigned char* w = (unsigned char*)d_ws;
  unsigned short* xb     = (unsigned short*)(w);             // 16 MB (T,D) bf16
  unsigned short* WqkvT  = (unsigned short*)(w + 16777216);  // 48 MB (6144,4096) bf16
  unsigned short* qkvraw = (unsigned short*)(w + 67108864);  // 24 MB (T,6144) bf16
  unsigned short* qbuf   = (unsigned short*)(w + 92274688);  // 16 MB (H,T,HD)
  unsigned short* kbuf   = (unsigned short*)(w + 109051904); // 4 MB (G,T,HD)
  unsigned short* vtb    = (unsigned short*)(w + 113246208); // 4 MB (G,HD,T) -> 117.4 MB
  unsigned short* WoT    = WqkvT;  // alias: Wqkv dead after QKV GEMM (32 MB of 48)
  unsigned short* attnb  = xb;     // alias: x dead after QKV GEMM

  convert_bf16<<<dim3(4096), dim3(256), 0, stream>>>(x, xb);
  // merged Wq/Wk/Wv transpose+convert: one dispatch, 96 output row-tiles
  transpose_convert_qkv<<<dim3(64, 96), dim3(256), 0, stream>>>(Wq, Wk, Wv, WqkvT);

  // fused QKV projection: (2048,4096) x (6144,4096)^T -> (2048,6144) bf16
  gemm5<3, 0><<<dim3(16, 32), dim3(256), 0, stream>>>(xb, WqkvT, (void*)qkvraw, 2048, 6144, 4096, 4096);

  // merged q+k RMSNorm+RoPE: one dispatch
  norm_rope2<<<dim3(20480), dim3(256), 0, stream>>>(qkvraw, qbuf, kbuf, qn, kn, cosT, sinT);
  transpose_v<<<dim3(32, 2, 8), dim3(256), 0, stream>>>(qkvraw + 5120, vtb, 6144);
  transpose_convert<<<dim3(64, 64), dim3(256), 0, stream>>>(Wo, WoT, 4096, 4096);

  // paired-uniform flash (R9 config): 256 identical blocks (33 tiles each)
  flash_attn<<<dim3(16, 16), dim3(512), 0, stream>>>(qbuf, kbuf, vtb, attnb);

  // Wo projection: BM=128, BN=128, 32x32 wave tile 64x64 -> grid (16,32), f32 out
  gemm5<2, 1><<<dim3(16, 32), dim3(256), 0, stream>>>(attnb, WoT, d_out, 2048, 4096, 4096, 4096);
}

// Round 17
// 317.353 us; speedup vs baseline: 1.0347x; 1.0347x over previous
//
#include <hip/hip_runtime.h>

#define T_ 2048
#define D_ 4096
#define H_ 32
#define G_ 8
#define HD_ 128

typedef float f32x4 __attribute__((ext_vector_type(4)));
typedef __bf16 bf16x8 __attribute__((ext_vector_type(8)));
typedef unsigned short u16x8 __attribute__((ext_vector_type(8)));
typedef unsigned short u16x4 __attribute__((ext_vector_type(4)));

__device__ __forceinline__ unsigned short f2bf(float f) {
  unsigned u = __builtin_bit_cast(unsigned, f);
  u += 0x7FFFu + ((u >> 16) & 1u);
  return (unsigned short)(u >> 16);
}
__device__ __forceinline__ float bf2f(unsigned short h) {
  return __builtin_bit_cast(float, (unsigned)h << 16);
}

__device__ __forceinline__ void gload_lds16(const unsigned short* g, unsigned short* l) {
  __builtin_amdgcn_global_load_lds((const __attribute__((address_space(1))) void*)g,
                                   (__attribute__((address_space(3))) void*)l, 16, 0, 0);
}

// ---------------- elementwise f32 -> bf16 ----------------
__global__ __launch_bounds__(256) void convert_bf16(const float* __restrict__ in,
                                                    unsigned short* __restrict__ out) {
  const size_t i = ((size_t)blockIdx.x * 256 + threadIdx.x) * 8;
  float4 a = *(const float4*)(in + i);
  float4 b = *(const float4*)(in + i + 4);
  u16x8 o;
  o[0] = f2bf(a.x); o[1] = f2bf(a.y); o[2] = f2bf(a.z); o[3] = f2bf(a.w);
  o[4] = f2bf(b.x); o[5] = f2bf(b.y); o[6] = f2bf(b.z); o[7] = f2bf(b.w);
  *(u16x8*)(out + i) = o;
}

// ---------------- single-W transpose + convert: W (R,C) f32 -> Wt (C,R) bf16 ----------------
__global__ __launch_bounds__(256) void transpose_convert(const float* __restrict__ Wm,
                                                         unsigned short* __restrict__ Wt,
                                                         int R, int C) {
  __shared__ float tile[64][65];
  const int r0 = blockIdx.x * 64, c0 = blockIdx.y * 64;
  const int lr4 = threadIdx.x >> 6, lc = threadIdx.x & 63;
#pragma unroll
  for (int i = 0; i < 16; ++i) {
    int r = i * 4 + lr4;
    tile[r][lc] = Wm[(size_t)(r0 + r) * C + c0 + lc];
  }
  __syncthreads();
#pragma unroll
  for (int i = 0; i < 16; ++i) {
    int r = i * 4 + lr4;
    Wt[(size_t)(c0 + r) * R + r0 + lc] = f2bf(tile[lc][r]);
  }
}

// ---------------- merged Wq/Wk/Wv transpose: out rows 0..6143 of WqkvT ----------------
__global__ __launch_bounds__(256) void transpose_convert_qkv(const float* __restrict__ Wq,
                                                             const float* __restrict__ Wk,
                                                             const float* __restrict__ Wv,
                                                             unsigned short* __restrict__ Wt) {
  __shared__ float tile[64][65];
  const int r0 = blockIdx.x * 64;
  const int cg = blockIdx.y * 64;  // output row base = concat source-col base
  const float* Wm;
  int C, c0;
  if (cg < 4096)      { Wm = Wq; C = 4096; c0 = cg; }
  else if (cg < 5120) { Wm = Wk; C = 1024; c0 = cg - 4096; }
  else                { Wm = Wv; C = 1024; c0 = cg - 5120; }
  const int lr4 = threadIdx.x >> 6, lc = threadIdx.x & 63;
#pragma unroll
  for (int i = 0; i < 16; ++i) {
    int r = i * 4 + lr4;
    tile[r][lc] = Wm[(size_t)(r0 + r) * C + c0 + lc];
  }
  __syncthreads();
#pragma unroll
  for (int i = 0; i < 16; ++i) {
    int r = i * 4 + lr4;
    Wt[(size_t)(cg + r) * 4096 + r0 + lc] = f2bf(tile[lc][r]);
  }
}

// ---------------- transpose v: (T, stride) bf16 cols -> (G, HD, T) bf16 ----------------
__global__ __launch_bounds__(256) void transpose_v(const unsigned short* __restrict__ v,
                                                   unsigned short* __restrict__ vt, int stride) {
  __shared__ unsigned short tile[64][65];
  const int t0 = blockIdx.x * 64, d0 = blockIdx.y * 64, g = blockIdx.z;
  const int lr4 = threadIdx.x >> 6, lc = threadIdx.x & 63;
#pragma unroll
  for (int i = 0; i < 16; ++i) {
    int r = i * 4 + lr4;
    tile[r][lc] = v[(size_t)(t0 + r) * stride + g * HD_ + d0 + lc];
  }
  __syncthreads();
#pragma unroll
  for (int i = 0; i < 16; ++i) {
    int r = i * 4 + lr4;
    vt[((size_t)g * HD_ + d0 + r) * T_ + t0 + lc] = tile[lc][r];
  }
}

// ---------------- merged RMSNorm + RoPE for q AND k ----------------
__global__ __launch_bounds__(256) void norm_rope2(const unsigned short* __restrict__ qkv,
                                                  unsigned short* __restrict__ qout,
                                                  unsigned short* __restrict__ kout,
                                                  const float* __restrict__ qw,
                                                  const float* __restrict__ kw,
                                                  const float* __restrict__ cs,
                                                  const float* __restrict__ sn) {
  int bid = blockIdx.x;
  const unsigned short* raw;
  unsigned short* outp;
  const float* w;
  int NH;
  if (bid < 16384) { raw = qkv;        outp = qout; w = qw; NH = 32; }
  else             { raw = qkv + 4096; outp = kout; w = kw; NH = 8; bid -= 16384; }
  const int row = bid * 4 + (threadIdx.x >> 6);
  const int lane = threadIdx.x & 63;
  const int t = row / NH, h = row - t * NH;
  const unsigned short* src = raw + (size_t)t * 6144 + h * HD_;
  float u1 = bf2f(src[lane]);
  float u2 = bf2f(src[lane + 64]);
  float ss = u1 * u1 + u2 * u2;
#pragma unroll
  for (int m = 1; m < 64; m <<= 1) ss += __shfl_xor(ss, m);
  float rr = rsqrtf(ss * (1.f / 128.f) + 1e-6f);
  float c = cs[(size_t)t * HD_ + lane];  // cos[d] == cos[d+64] (concat(freqs,freqs))
  float s = sn[(size_t)t * HD_ + lane];
  float a = u1 * rr * w[lane];
  float b = u2 * rr * w[lane + 64];
  unsigned short* dst = outp + ((size_t)h * T_ + t) * HD_;
  dst[lane]      = f2bf(a * c - b * s);
  dst[lane + 64] = f2bf(b * c + a * s);
}

// ---------------- 128 x (32*NFW) GEMM, 4 waves (2x2), 2 blocks/CU ----------------
// MERGED-REGION schedule: all 20 ds_reads issue first (bfL/bfU separate regs),
// then stageB(t+1), then MFMA-lower (compiler interleaves lgkmcnt waits under
// the MFMAs), ONE mid barrier, stageA(t+2), MFMA-upper covers the DMA latency.
// Counted vmcnt(4) at step end (never 0 mid-loop): retires exactly A(t+1)+B(t+1),
// keeps A(t+2) in flight. 16x16 MFMA: fragment reads touch 16 rows -> 2-way LDS
// aliasing = free (32x32 tried in R16: inherent 4-way conflict, regressed).
// Swizzle (rule #21 involution): linear LDS dest, global src col ^= row&7, reads same XOR.
template <int NFW, int OUTF32>
__global__ __launch_bounds__(256, 2) void gemm4(const unsigned short* __restrict__ A,
                                                const unsigned short* __restrict__ Bt,
                                                void* __restrict__ Cv, int M, int N,
                                                int K, int LDA) {
  constexpr int BN = 32 * NFW;        // 192 (NFW=6) or 128 (NFW=4)
  constexpr int ABUF = 8192;          // ushorts per A dbuf (128x64)
  constexpr int BBUF = BN * 64;       // ushorts per B dbuf
  constexpr int NH = NFW / 2;
  __shared__ __align__(16) unsigned short lds[2 * ABUF + 2 * BBUF];
  const int tid = threadIdx.x;
  const int wid = tid >> 6, lane = tid & 63;
  const int lr = lane & 15, lhi = lane >> 4;
  const int wr = wid >> 1, wcn = wid & 1;

  // XCD-aware swizzle (nwg = 512, bijective); gridDim.x == 16 row-blocks
  int flat = blockIdx.y * gridDim.x + blockIdx.x;
  int nwg = gridDim.x * gridDim.y;
  int swz = (flat & 7) * (nwg >> 3) + (flat >> 3);
  const int brow = (swz & 15) * 128;
  const int bcol = (swz >> 4) * BN;

  const int nt = K >> 6;

  f32x4 acc[4][NFW];
#pragma unroll
  for (int b = 0; b < 4; ++b)
#pragma unroll
    for (int c = 0; c < NFW; ++c) acc[b][c] = (f32x4){0.f, 0.f, 0.f, 0.f};

  // staging: unit = 64 rows x 64 cols bf16 (8 KB) = 256 thr x 2 x 16 B
  const int t8 = tid >> 3;                        // row within 32-row half-unit
  const int srcCol = ((tid & 7) ^ (t8 & 7)) * 8;  // inverse-swizzled source col
  auto stageA = [&](int d, int u, int ktp) {
#pragma unroll
    for (int l = 0; l < 2; ++l)
      gload_lds16(A + (size_t)(brow + u * 64 + l * 32 + t8) * LDA + ktp * 64 + srcCol,
                  &lds[d * ABUF + u * 4096 + l * 2048 + tid * 8]);
  };
  auto stageB = [&](int d, int v, int ktp) {
#pragma unroll
    for (int l = 0; l < 2; ++l)
      gload_lds16(Bt + (size_t)(bcol + v * 64 + l * 32 + t8) * LDA + ktp * 64 + srcCol,
                  &lds[2 * ABUF + d * BBUF + v * 4096 + l * 2048 + tid * 8]);
  };

  bf16x8 af[4][2], bfL[NH][2], bfU[NH][2];
  auto readA = [&](int d) {
#pragma unroll
    for (int fm = 0; fm < 4; ++fm) {
      int row = wr * 64 + fm * 16 + lr;
      int base = d * ABUF + row * 64;
      int sw = (row & 7) << 3;
      af[fm][0] = *(const bf16x8*)&lds[base + ((lhi * 8) ^ sw)];
      af[fm][1] = *(const bf16x8*)&lds[base + ((32 + lhi * 8) ^ sw)];
    }
  };
  auto readBf = [&](int d, int fn, bf16x8 (&slot)[2]) {
    int row = wcn * (16 * NFW) + fn * 16 + lr;
    int base = 2 * ABUF + d * BBUF + row * 64;
    int sw = (row & 7) << 3;
    slot[0] = *(const bf16x8*)&lds[base + ((lhi * 8) ^ sw)];
    slot[1] = *(const bf16x8*)&lds[base + ((32 + lhi * 8) ^ sw)];
  };

  // prologue: step0 full -> d0; A(step1) -> d1 (nt >= 2 here)
  stageA(0, 0, 0); stageA(0, 1, 0);
#pragma unroll
  for (int v = 0; v < NH; ++v) stageB(0, v, 0);
  stageA(1, 0, 1); stageA(1, 1, 1);
  asm volatile("s_waitcnt vmcnt(4)" ::: "memory");
  __builtin_amdgcn_s_barrier();

  for (int t = 0; t < nt; ++t) {
    const int d = t & 1, dn = d ^ 1;
    // all ds_reads first (A + both B halves, independent regs)
    readA(d);
#pragma unroll
    for (int j = 0; j < NH; ++j) readBf(d, j, bfL[j]);
#pragma unroll
    for (int j = 0; j < NH; ++j) readBf(d, NH + j, bfU[j]);
    // stage next-step B into the other dbuf
    if (t + 1 < nt) {
#pragma unroll
      for (int v = 0; v < NH; ++v) stageB(dn, v, t + 1);
    }
    // MFMA lower half: compiler interleaves the pending ds_reads under these
#pragma unroll
    for (int fm = 0; fm < 4; ++fm)
#pragma unroll
      for (int j = 0; j < NH; ++j) {
        f32x4 a = acc[fm][j];
        a = __builtin_amdgcn_mfma_f32_16x16x32_bf16(af[fm][0], bfL[j][0], a, 0, 0, 0);
        a = __builtin_amdgcn_mfma_f32_16x16x32_bf16(af[fm][1], bfL[j][1], a, 0, 0, 0);
        acc[fm][j] = a;
      }
    // all waves' A-reads issued -> safe to overwrite A slots of dbuf d
    __builtin_amdgcn_s_barrier();
    if (t + 2 < nt) { stageA(d, 0, t + 2); stageA(d, 1, t + 2); }
    // MFMA upper half covers the stageA DMA latency
#pragma unroll
    for (int fm = 0; fm < 4; ++fm)
#pragma unroll
      for (int j = 0; j < NH; ++j) {
        f32x4 a = acc[fm][NH + j];
        a = __builtin_amdgcn_mfma_f32_16x16x32_bf16(af[fm][0], bfU[j][0], a, 0, 0, 0);
        a = __builtin_amdgcn_mfma_f32_16x16x32_bf16(af[fm][1], bfU[j][1], a, 0, 0, 0);
        acc[fm][NH + j] = a;
      }
    if (t < nt - 2) asm volatile("s_waitcnt vmcnt(4)" ::: "memory");
    else if (t == nt - 2) asm volatile("s_waitcnt vmcnt(0)" ::: "memory");
    __builtin_amdgcn_s_barrier();
  }

  // epilogue
#pragma unroll
  for (int fm = 0; fm < 4; ++fm)
#pragma unroll
    for (int fn = 0; fn < NFW; ++fn) {
      int col = bcol + wcn * (16 * NFW) + fn * 16 + lr;
#pragma unroll
      for (int r = 0; r < 4; ++r) {
        int row = brow + wr * 64 + fm * 16 + lhi * 4 + r;
        if (OUTF32)
          ((float*)Cv)[(size_t)row * N + col] = acc[fm][fn][r];
        else
          ((unsigned short*)Cv)[(size_t)row * N + col] = f2bf(acc[fm][fn][r]);
      }
    }
}

// ---------------- causal flash attention: 2 heads/block, PAIRED q-chunks (R9 verbatim) ----------------
__global__ __launch_bounds__(512) void flash_attn(const unsigned short* __restrict__ q,
                                                  const unsigned short* __restrict__ k,
                                                  const unsigned short* __restrict__ vt,
                                                  unsigned short* __restrict__ attnb) {
  const int pairIdx = blockIdx.y;
  const int g = pairIdx >> 1;  // GS = 4, 2 heads/block
  const int qcp = blockIdx.x;  // pair slot: chunks {qcp, 31-qcp}
  const int tid = threadIdx.x;
  const int wid = tid >> 6;
  const int lane = tid & 63;
  const int lr = lane & 15, lhi = lane >> 4;
  const int h = pairIdx * 2 + (wid >> 2);

  __shared__ __align__(16) unsigned short Ks[2][64 * HD_];
  __shared__ __align__(16) unsigned short Vs[2][HD_ * 64];
  __shared__ __align__(16) unsigned short p_lds_all[8][16 * 64];
  unsigned short* p_lds = p_lds_all[wid];

  const unsigned short* kg = k + (size_t)g * T_ * HD_;
  const unsigned short* vg = vt + (size_t)g * HD_ * T_;

  int ko[2], vo[2];
#pragma unroll
  for (int p = 0; p < 2; ++p) {
    int ob = (p * 512 + tid) * 16;
    int krow = ob >> 8, kb = ob & 255;
    ko[p] = krow * HD_ + ((kb ^ ((krow & 7) << 4)) >> 1);
    int vrow = ob >> 7, vb2 = ob & 127;
    vo[p] = vrow * T_ + ((vb2 ^ ((vrow & 7) << 4)) >> 1);
  }
  const int lbase = wid * 512;

  const int sx = (lr & 7) << 4;
  const float scale2 = 0.08838834764831845f * 1.4426950408889634f;

  for (int pass = 0; pass < 2; ++pass) {
    const int qc = pass ? (31 - qcp) : qcp;
    const int q0 = qc * 64 + (wid & 3) * 16;

    bf16x8 qf[4];
    {
      const unsigned short* qrow = q + ((size_t)h * T_ + q0 + lr) * HD_ + lhi * 8;
#pragma unroll
      for (int c = 0; c < 4; ++c) qf[c] = *(const bf16x8*)(qrow + c * 32);
    }
    f32x4 accO[8];
#pragma unroll
    for (int i = 0; i < 8; ++i) accO[i] = (f32x4){0.f, 0.f, 0.f, 0.f};
    float mrow = -3e38f;
    float lrow = 0.f;

    const int ntile = qc + 1;

    // prologue: stage tile 0 into buffer 0 (previous pass fully drained)
#pragma unroll
    for (int p = 0; p < 2; ++p) {
      gload_lds16(kg + ko[p], &Ks[0][p * 4096 + lbase]);
      gload_lds16(vg + vo[p], &Vs[0][p * 4096 + lbase]);
    }
    __syncthreads();

    for (int kt = 0; kt < ntile; ++kt) {
      const int b = kt & 1;
      const int kv0 = kt << 6;
      if (kt + 1 < ntile) {
        const size_t kofs = (size_t)(kv0 + 64) * HD_;
#pragma unroll
        for (int p = 0; p < 2; ++p) {
          gload_lds16(kg + kofs + ko[p], &Ks[b ^ 1][p * 4096 + lbase]);
          gload_lds16(vg + (kv0 + 64) + vo[p], &Vs[b ^ 1][p * 4096 + lbase]);
        }
      }
      f32x4 st[4];
      __builtin_amdgcn_s_setprio(1);
#pragma unroll
      for (int j = 0; j < 4; ++j) {
        st[j] = (f32x4){0.f, 0.f, 0.f, 0.f};
        const int krow = j * 16 + lr;
#pragma unroll
        for (int c = 0; c < 4; ++c) {
          bf16x8 kf = *(const bf16x8*)&Ks[b][krow * HD_ + (((c * 64 + lhi * 16) ^ sx) >> 1)];
          st[j] = __builtin_amdgcn_mfma_f32_16x16x32_bf16(kf, qf[c], st[j], 0, 0, 0);
        }
      }
      __builtin_amdgcn_s_setprio(0);
      if (kt == ntile - 1) {
#pragma unroll
        for (int j = 0; j < 4; ++j)
#pragma unroll
          for (int r = 0; r < 4; ++r)
            st[j][r] = (kv0 + j * 16 + lhi * 4 + r <= q0 + lr) ? st[j][r] * scale2 : -3e38f;
      } else {
#pragma unroll
        for (int j = 0; j < 4; ++j)
#pragma unroll
          for (int r = 0; r < 4; ++r) st[j][r] *= scale2;
      }
      float pm = st[0][0];
#pragma unroll
      for (int j = 0; j < 4; ++j)
#pragma unroll
        for (int r = 0; r < 4; ++r) pm = fmaxf(pm, st[j][r]);
      pm = fmaxf(pm, __shfl_xor(pm, 16));
      pm = fmaxf(pm, __shfl_xor(pm, 32));
      if (!__all(pm - mrow <= 8.f)) {
        float mnew = fmaxf(mrow, pm);
        float al = __builtin_amdgcn_exp2f(mrow - mnew);
        mrow = mnew;
        lrow *= al;
        float a0 = __shfl(al, lhi * 4 + 0);
        float a1 = __shfl(al, lhi * 4 + 1);
        float a2 = __shfl(al, lhi * 4 + 2);
        float a3 = __shfl(al, lhi * 4 + 3);
#pragma unroll
        for (int dt = 0; dt < 8; ++dt) {
          accO[dt][0] *= a0; accO[dt][1] *= a1; accO[dt][2] *= a2; accO[dt][3] *= a3;
        }
      }
      float ps = 0.f;
#pragma unroll
      for (int j = 0; j < 4; ++j)
#pragma unroll
        for (int r = 0; r < 4; ++r) {
          float e = __builtin_amdgcn_exp2f(st[j][r] - mrow);
          st[j][r] = e;
          ps += e;
        }
      ps += __shfl_xor(ps, 16);
      ps += __shfl_xor(ps, 32);
      lrow += ps;
#pragma unroll
      for (int j = 0; j < 4; ++j) {
        u16x4 pw;
        pw[0] = f2bf(st[j][0]); pw[1] = f2bf(st[j][1]);
        pw[2] = f2bf(st[j][2]); pw[3] = f2bf(st[j][3]);
        *(u16x4*)&p_lds[lr * 64 + (((j * 32 + lhi * 8) ^ sx) >> 1)] = pw;
      }
      bf16x8 pa0 = *(const bf16x8*)&p_lds[lr * 64 + (((lhi * 16) ^ sx) >> 1)];
      bf16x8 pa1 = *(const bf16x8*)&p_lds[lr * 64 + (((64 + lhi * 16) ^ sx) >> 1)];
      __builtin_amdgcn_s_setprio(1);
#pragma unroll
      for (int dt = 0; dt < 8; ++dt) {
        const int vrow = dt * 16 + lr;
        bf16x8 vf0 = *(const bf16x8*)&Vs[b][vrow * 64 + (((lhi * 16) ^ sx) >> 1)];
        bf16x8 vf1 = *(const bf16x8*)&Vs[b][vrow * 64 + (((64 + lhi * 16) ^ sx) >> 1)];
        accO[dt] = __builtin_amdgcn_mfma_f32_16x16x32_bf16(pa0, vf0, accO[dt], 0, 0, 0);
        accO[dt] = __builtin_amdgcn_mfma_f32_16x16x32_bf16(pa1, vf1, accO[dt], 0, 0, 0);
      }
      __builtin_amdgcn_s_setprio(0);
      __syncthreads();
    }
    float rinv = 1.f / lrow;
    float i0 = __shfl(rinv, lhi * 4 + 0);
    float i1 = __shfl(rinv, lhi * 4 + 1);
    float i2 = __shfl(rinv, lhi * 4 + 2);
    float i3 = __shfl(rinv, lhi * 4 + 3);
    float iv[4] = {i0, i1, i2, i3};
#pragma unroll
    for (int r = 0; r < 4; ++r) {
      size_t rowoff = (size_t)(q0 + lhi * 4 + r) * (H_ * HD_) + h * HD_;
#pragma unroll
      for (int dt = 0; dt < 8; ++dt) attnb[rowoff + dt * 16 + lr] = f2bf(accO[dt][r] * iv[r]);
    }
  }
}

extern "C" void kernel_launch(void* const* d_in, const int* in_sizes, int n_in,
                              void* d_out, int out_size, void* d_ws, size_t ws_size,
                              hipStream_t stream) {
  const float* x = (const float*)d_in[0];
  // d_in[1] = mask (bool) — causal mask computed analytically, unused
  const float* cosT = (const float*)d_in[2];
  const float* sinT = (const float*)d_in[3];
  const float* Wq = (const float*)d_in[4];
  const float* Wk = (const float*)d_in[5];
  const float* Wv = (const float*)d_in[6];
  const float* Wo = (const float*)d_in[7];
  const float* qn = (const float*)d_in[8];
  const float* kn = (const float*)d_in[9];

  unsigned char* w = (unsigned char*)d_ws;
  unsigned short* xb     = (unsigned short*)(w);             // 16 MB (T,D) bf16
  unsigned short* WqkvT  = (unsigned short*)(w + 16777216);  // 48 MB (6144,4096) bf16
  unsigned short* qkvraw = (unsigned short*)(w + 67108864);  // 24 MB (T,6144) bf16
  unsigned short* qbuf   = (unsigned short*)(w + 92274688);  // 16 MB (H,T,HD)
  unsigned short* kbuf   = (unsigned short*)(w + 109051904); // 4 MB (G,T,HD)
  unsigned short* vtb    = (unsigned short*)(w + 113246208); // 4 MB (G,HD,T) -> 117.4 MB
  unsigned short* WoT    = WqkvT;  // alias: Wqkv dead after QKV GEMM (32 MB of 48)
  unsigned short* attnb  = xb;     // alias: x dead after QKV GEMM

  convert_bf16<<<dim3(4096), dim3(256), 0, stream>>>(x, xb);
  // merged Wq/Wk/Wv transpose+convert: one dispatch, 96 output row-tiles
  transpose_convert_qkv<<<dim3(64, 96), dim3(256), 0, stream>>>(Wq, Wk, Wv, WqkvT);

  // fused QKV projection: (2048,4096) x (6144,4096)^T -> (2048,6144) bf16
  gemm4<6, 0><<<dim3(16, 32), dim3(256), 0, stream>>>(xb, WqkvT, (void*)qkvraw, 2048, 6144, 4096, 4096);

  // merged q+k RMSNorm+RoPE: one dispatch
  norm_rope2<<<dim3(20480), dim3(256), 0, stream>>>(qkvraw, qbuf, kbuf, qn, kn, cosT, sinT);
  transpose_v<<<dim3(32, 2, 8), dim3(256), 0, stream>>>(qkvraw + 5120, vtb, 6144);
  transpose_convert<<<dim3(64, 64), dim3(256), 0, stream>>>(Wo, WoT, 4096, 4096);

  // paired-uniform flash (R9 config): 256 identical blocks (33 tiles each)
  flash_attn<<<dim3(16, 16), dim3(512), 0, stream>>>(qbuf, kbuf, vtb, attnb);

  // Wo projection: BM=128, BN=128, 4-wave 64x64 wave tile -> grid (16,32), f32 out
  gemm4<4, 1><<<dim3(16, 32), dim3(256), 0, stream>>>(attnb, WoT, d_out, 2048, 4096, 4096, 4096);
}

// Round 18
// 316.031 us; speedup vs baseline: 1.0390x; 1.0042x over previous
//
#include <hip/hip_runtime.h>

#define T_ 2048
#define D_ 4096
#define H_ 32
#define G_ 8
#define HD_ 128

typedef float f32x4 __attribute__((ext_vector_type(4)));
typedef __bf16 bf16x8 __attribute__((ext_vector_type(8)));
typedef unsigned short u16x8 __attribute__((ext_vector_type(8)));
typedef unsigned short u16x4 __attribute__((ext_vector_type(4)));

__device__ __forceinline__ unsigned short f2bf(float f) {
  unsigned u = __builtin_bit_cast(unsigned, f);
  u += 0x7FFFu + ((u >> 16) & 1u);
  return (unsigned short)(u >> 16);
}
__device__ __forceinline__ float bf2f(unsigned short h) {
  return __builtin_bit_cast(float, (unsigned)h << 16);
}

__device__ __forceinline__ void gload_lds16(const unsigned short* g, unsigned short* l) {
  __builtin_amdgcn_global_load_lds((const __attribute__((address_space(1))) void*)g,
                                   (__attribute__((address_space(3))) void*)l, 16, 0, 0);
}

// ---------------- elementwise f32 -> bf16 ----------------
__global__ __launch_bounds__(256) void convert_bf16(const float* __restrict__ in,
                                                    unsigned short* __restrict__ out) {
  const size_t i = ((size_t)blockIdx.x * 256 + threadIdx.x) * 8;
  float4 a = *(const float4*)(in + i);
  float4 b = *(const float4*)(in + i + 4);
  u16x8 o;
  o[0] = f2bf(a.x); o[1] = f2bf(a.y); o[2] = f2bf(a.z); o[3] = f2bf(a.w);
  o[4] = f2bf(b.x); o[5] = f2bf(b.y); o[6] = f2bf(b.z); o[7] = f2bf(b.w);
  *(u16x8*)(out + i) = o;
}

// ---------------- single-W transpose + convert: W (R,C) f32 -> Wt (C,R) bf16 ----------------
__global__ __launch_bounds__(256) void transpose_convert(const float* __restrict__ Wm,
                                                         unsigned short* __restrict__ Wt,
                                                         int R, int C) {
  __shared__ float tile[64][65];
  const int r0 = blockIdx.x * 64, c0 = blockIdx.y * 64;
  const int lr4 = threadIdx.x >> 6, lc = threadIdx.x & 63;
#pragma unroll
  for (int i = 0; i < 16; ++i) {
    int r = i * 4 + lr4;
    tile[r][lc] = Wm[(size_t)(r0 + r) * C + c0 + lc];
  }
  __syncthreads();
#pragma unroll
  for (int i = 0; i < 16; ++i) {
    int r = i * 4 + lr4;
    Wt[(size_t)(c0 + r) * R + r0 + lc] = f2bf(tile[lc][r]);
  }
}

// ---------------- merged Wq/Wk/Wv transpose: out rows 0..6143 of WqkvT ----------------
__global__ __launch_bounds__(256) void transpose_convert_qkv(const float* __restrict__ Wq,
                                                             const float* __restrict__ Wk,
                                                             const float* __restrict__ Wv,
                                                             unsigned short* __restrict__ Wt) {
  __shared__ float tile[64][65];
  const int r0 = blockIdx.x * 64;
  const int cg = blockIdx.y * 64;  // output row base = concat source-col base
  const float* Wm;
  int C, c0;
  if (cg < 4096)      { Wm = Wq; C = 4096; c0 = cg; }
  else if (cg < 5120) { Wm = Wk; C = 1024; c0 = cg - 4096; }
  else                { Wm = Wv; C = 1024; c0 = cg - 5120; }
  const int lr4 = threadIdx.x >> 6, lc = threadIdx.x & 63;
#pragma unroll
  for (int i = 0; i < 16; ++i) {
    int r = i * 4 + lr4;
    tile[r][lc] = Wm[(size_t)(r0 + r) * C + c0 + lc];
  }
  __syncthreads();
#pragma unroll
  for (int i = 0; i < 16; ++i) {
    int r = i * 4 + lr4;
    Wt[(size_t)(cg + r) * 4096 + r0 + lc] = f2bf(tile[lc][r]);
  }
}

// ---------------- merged post-QKV: RMSNorm+RoPE (q,k) AND V transpose ----------------
// blocks [0, 16384): q rows (NH=32); [16384, 20480): k rows (NH=8);
// [20480, 20992): V transpose tiles (T,6144 slice +5120) -> (G, HD, T).
__global__ __launch_bounds__(256) void post_qkv(const unsigned short* __restrict__ qkv,
                                                unsigned short* __restrict__ qout,
                                                unsigned short* __restrict__ kout,
                                                unsigned short* __restrict__ vt,
                                                const float* __restrict__ qw,
                                                const float* __restrict__ kw,
                                                const float* __restrict__ cs,
                                                const float* __restrict__ sn) {
  __shared__ unsigned short tile[64][65];
  int bid = blockIdx.x;
  if (bid >= 20480) {
    // ---- V transpose tile ----
    int idx = bid - 20480;                 // [0,512)
    const int t0 = (idx & 31) * 64;
    const int d0 = ((idx >> 5) & 1) * 64;
    const int g = idx >> 6;
    const unsigned short* v = qkv + 5120;  // stride 6144
    const int lr4 = threadIdx.x >> 6, lc = threadIdx.x & 63;
#pragma unroll
    for (int i = 0; i < 16; ++i) {
      int r = i * 4 + lr4;
      tile[r][lc] = v[(size_t)(t0 + r) * 6144 + g * HD_ + d0 + lc];
    }
    __syncthreads();
#pragma unroll
    for (int i = 0; i < 16; ++i) {
      int r = i * 4 + lr4;
      vt[((size_t)g * HD_ + d0 + r) * T_ + t0 + lc] = tile[lc][r];
    }
    return;
  }
  // ---- RMSNorm + RoPE ----
  const unsigned short* raw;
  unsigned short* outp;
  const float* w;
  int NH;
  if (bid < 16384) { raw = qkv;        outp = qout; w = qw; NH = 32; }
  else             { raw = qkv + 4096; outp = kout; w = kw; NH = 8; bid -= 16384; }
  const int row = bid * 4 + (threadIdx.x >> 6);
  const int lane = threadIdx.x & 63;
  const int t = row / NH, h = row - t * NH;
  const unsigned short* src = raw + (size_t)t * 6144 + h * HD_;
  float u1 = bf2f(src[lane]);
  float u2 = bf2f(src[lane + 64]);
  float ss = u1 * u1 + u2 * u2;
#pragma unroll
  for (int m = 1; m < 64; m <<= 1) ss += __shfl_xor(ss, m);
  float rr = rsqrtf(ss * (1.f / 128.f) + 1e-6f);
  float c = cs[(size_t)t * HD_ + lane];  // cos[d] == cos[d+64] (concat(freqs,freqs))
  float s = sn[(size_t)t * HD_ + lane];
  float a = u1 * rr * w[lane];
  float b = u2 * rr * w[lane + 64];
  unsigned short* dst = outp + ((size_t)h * T_ + t) * HD_;
  dst[lane]      = f2bf(a * c - b * s);
  dst[lane + 64] = f2bf(b * c + a * s);
}

// ---------------- 128 x (32*NFW) GEMM, 4 waves (2x2), 2 blocks/CU ----------------
// MERGED-REGION schedule: all 20 ds_reads issue first (bfL/bfU separate regs),
// then stageB(t+1), then MFMA-lower (compiler interleaves lgkmcnt waits under
// the MFMAs), ONE mid barrier, stageA(t+2), MFMA-upper covers the DMA latency.
// Counted vmcnt(4) at step end (never 0 mid-loop): retires exactly A(t+1)+B(t+1),
// keeps A(t+2) in flight. 16x16 MFMA: fragment reads touch 16 rows -> 2-way LDS
// aliasing = free (32x32 tried in R16: inherent 4-way conflict, regressed).
// Swizzle (rule #21 involution): linear LDS dest, global src col ^= row&7, reads same XOR.
template <int NFW, int OUTF32>
__global__ __launch_bounds__(256, 2) void gemm4(const unsigned short* __restrict__ A,
                                                const unsigned short* __restrict__ Bt,
                                                void* __restrict__ Cv, int M, int N,
                                                int K, int LDA) {
  constexpr int BN = 32 * NFW;        // 192 (NFW=6) or 128 (NFW=4)
  constexpr int ABUF = 8192;          // ushorts per A dbuf (128x64)
  constexpr int BBUF = BN * 64;       // ushorts per B dbuf
  constexpr int NH = NFW / 2;
  __shared__ __align__(16) unsigned short lds[2 * ABUF + 2 * BBUF];
  const int tid = threadIdx.x;
  const int wid = tid >> 6, lane = tid & 63;
  const int lr = lane & 15, lhi = lane >> 4;
  const int wr = wid >> 1, wcn = wid & 1;

  // XCD-aware swizzle (nwg = 512, bijective); gridDim.x == 16 row-blocks
  int flat = blockIdx.y * gridDim.x + blockIdx.x;
  int nwg = gridDim.x * gridDim.y;
  int swz = (flat & 7) * (nwg >> 3) + (flat >> 3);
  const int brow = (swz & 15) * 128;
  const int bcol = (swz >> 4) * BN;

  const int nt = K >> 6;

  f32x4 acc[4][NFW];
#pragma unroll
  for (int b = 0; b < 4; ++b)
#pragma unroll
    for (int c = 0; c < NFW; ++c) acc[b][c] = (f32x4){0.f, 0.f, 0.f, 0.f};

  // staging: unit = 64 rows x 64 cols bf16 (8 KB) = 256 thr x 2 x 16 B
  const int t8 = tid >> 3;                        // row within 32-row half-unit
  const int srcCol = ((tid & 7) ^ (t8 & 7)) * 8;  // inverse-swizzled source col
  auto stageA = [&](int d, int u, int ktp) {
#pragma unroll
    for (int l = 0; l < 2; ++l)
      gload_lds16(A + (size_t)(brow + u * 64 + l * 32 + t8) * LDA + ktp * 64 + srcCol,
                  &lds[d * ABUF + u * 4096 + l * 2048 + tid * 8]);
  };
  auto stageB = [&](int d, int v, int ktp) {
#pragma unroll
    for (int l = 0; l < 2; ++l)
      gload_lds16(Bt + (size_t)(bcol + v * 64 + l * 32 + t8) * LDA + ktp * 64 + srcCol,
                  &lds[2 * ABUF + d * BBUF + v * 4096 + l * 2048 + tid * 8]);
  };

  bf16x8 af[4][2], bfL[NH][2], bfU[NH][2];
  auto readA = [&](int d) {
#pragma unroll
    for (int fm = 0; fm < 4; ++fm) {
      int row = wr * 64 + fm * 16 + lr;
      int base = d * ABUF + row * 64;
      int sw = (row & 7) << 3;
      af[fm][0] = *(const bf16x8*)&lds[base + ((lhi * 8) ^ sw)];
      af[fm][1] = *(const bf16x8*)&lds[base + ((32 + lhi * 8) ^ sw)];
    }
  };
  auto readBf = [&](int d, int fn, bf16x8 (&slot)[2]) {
    int row = wcn * (16 * NFW) + fn * 16 + lr;
    int base = 2 * ABUF + d * BBUF + row * 64;
    int sw = (row & 7) << 3;
    slot[0] = *(const bf16x8*)&lds[base + ((lhi * 8) ^ sw)];
    slot[1] = *(const bf16x8*)&lds[base + ((32 + lhi * 8) ^ sw)];
  };

  // prologue: step0 full -> d0; A(step1) -> d1 (nt >= 2 here)
  stageA(0, 0, 0); stageA(0, 1, 0);
#pragma unroll
  for (int v = 0; v < NH; ++v) stageB(0, v, 0);
  stageA(1, 0, 1); stageA(1, 1, 1);
  asm volatile("s_waitcnt vmcnt(4)" ::: "memory");
  __builtin_amdgcn_s_barrier();

  for (int t = 0; t < nt; ++t) {
    const int d = t & 1, dn = d ^ 1;
    // all ds_reads first (A + both B halves, independent regs)
    readA(d);
#pragma unroll
    for (int j = 0; j < NH; ++j) readBf(d, j, bfL[j]);
#pragma unroll
    for (int j = 0; j < NH; ++j) readBf(d, NH + j, bfU[j]);
    // stage next-step B into the other dbuf
    if (t + 1 < nt) {
#pragma unroll
      for (int v = 0; v < NH; ++v) stageB(dn, v, t + 1);
    }
    // MFMA lower half: compiler interleaves the pending ds_reads under these
#pragma unroll
    for (int fm = 0; fm < 4; ++fm)
#pragma unroll
      for (int j = 0; j < NH; ++j) {
        f32x4 a = acc[fm][j];
        a = __builtin_amdgcn_mfma_f32_16x16x32_bf16(af[fm][0], bfL[j][0], a, 0, 0, 0);
        a = __builtin_amdgcn_mfma_f32_16x16x32_bf16(af[fm][1], bfL[j][1], a, 0, 0, 0);
        acc[fm][j] = a;
      }
    // all waves' A-reads issued -> safe to overwrite A slots of dbuf d
    __builtin_amdgcn_s_barrier();
    if (t + 2 < nt) { stageA(d, 0, t + 2); stageA(d, 1, t + 2); }
    // MFMA upper half covers the stageA DMA latency
#pragma unroll
    for (int fm = 0; fm < 4; ++fm)
#pragma unroll
      for (int j = 0; j < NH; ++j) {
        f32x4 a = acc[fm][NH + j];
        a = __builtin_amdgcn_mfma_f32_16x16x32_bf16(af[fm][0], bfU[j][0], a, 0, 0, 0);
        a = __builtin_amdgcn_mfma_f32_16x16x32_bf16(af[fm][1], bfU[j][1], a, 0, 0, 0);
        acc[fm][NH + j] = a;
      }
    if (t < nt - 2) asm volatile("s_waitcnt vmcnt(4)" ::: "memory");
    else if (t == nt - 2) asm volatile("s_waitcnt vmcnt(0)" ::: "memory");
    __builtin_amdgcn_s_barrier();
  }

  // epilogue
#pragma unroll
  for (int fm = 0; fm < 4; ++fm)
#pragma unroll
    for (int fn = 0; fn < NFW; ++fn) {
      int col = bcol + wcn * (16 * NFW) + fn * 16 + lr;
#pragma unroll
      for (int r = 0; r < 4; ++r) {
        int row = brow + wr * 64 + fm * 16 + lhi * 4 + r;
        if (OUTF32)
          ((float*)Cv)[(size_t)row * N + col] = acc[fm][fn][r];
        else
          ((unsigned short*)Cv)[(size_t)row * N + col] = f2bf(acc[fm][fn][r]);
      }
    }
}

// ---------------- causal flash attention: 2 heads/block, PAIRED q-chunks (R9 verbatim) ----------------
__global__ __launch_bounds__(512) void flash_attn(const unsigned short* __restrict__ q,
                                                  const unsigned short* __restrict__ k,
                                                  const unsigned short* __restrict__ vt,
                                                  unsigned short* __restrict__ attnb) {
  const int pairIdx = blockIdx.y;
  const int g = pairIdx >> 1;  // GS = 4, 2 heads/block
  const int qcp = blockIdx.x;  // pair slot: chunks {qcp, 31-qcp}
  const int tid = threadIdx.x;
  const int wid = tid >> 6;
  const int lane = tid & 63;
  const int lr = lane & 15, lhi = lane >> 4;
  const int h = pairIdx * 2 + (wid >> 2);

  __shared__ __align__(16) unsigned short Ks[2][64 * HD_];
  __shared__ __align__(16) unsigned short Vs[2][HD_ * 64];
  __shared__ __align__(16) unsigned short p_lds_all[8][16 * 64];
  unsigned short* p_lds = p_lds_all[wid];

  const unsigned short* kg = k + (size_t)g * T_ * HD_;
  const unsigned short* vg = vt + (size_t)g * HD_ * T_;

  int ko[2], vo[2];
#pragma unroll
  for (int p = 0; p < 2; ++p) {
    int ob = (p * 512 + tid) * 16;
    int krow = ob >> 8, kb = ob & 255;
    ko[p] = krow * HD_ + ((kb ^ ((krow & 7) << 4)) >> 1);
    int vrow = ob >> 7, vb2 = ob & 127;
    vo[p] = vrow * T_ + ((vb2 ^ ((vrow & 7) << 4)) >> 1);
  }
  const int lbase = wid * 512;

  const int sx = (lr & 7) << 4;
  const float scale2 = 0.08838834764831845f * 1.4426950408889634f;

  for (int pass = 0; pass < 2; ++pass) {
    const int qc = pass ? (31 - qcp) : qcp;
    const int q0 = qc * 64 + (wid & 3) * 16;

    bf16x8 qf[4];
    {
      const unsigned short* qrow = q + ((size_t)h * T_ + q0 + lr) * HD_ + lhi * 8;
#pragma unroll
      for (int c = 0; c < 4; ++c) qf[c] = *(const bf16x8*)(qrow + c * 32);
    }
    f32x4 accO[8];
#pragma unroll
    for (int i = 0; i < 8; ++i) accO[i] = (f32x4){0.f, 0.f, 0.f, 0.f};
    float mrow = -3e38f;
    float lrow = 0.f;

    const int ntile = qc + 1;

    // prologue: stage tile 0 into buffer 0 (previous pass fully drained)
#pragma unroll
    for (int p = 0; p < 2; ++p) {
      gload_lds16(kg + ko[p], &Ks[0][p * 4096 + lbase]);
      gload_lds16(vg + vo[p], &Vs[0][p * 4096 + lbase]);
    }
    __syncthreads();

    for (int kt = 0; kt < ntile; ++kt) {
      const int b = kt & 1;
      const int kv0 = kt << 6;
      if (kt + 1 < ntile) {
        const size_t kofs = (size_t)(kv0 + 64) * HD_;
#pragma unroll
        for (int p = 0; p < 2; ++p) {
          gload_lds16(kg + kofs + ko[p], &Ks[b ^ 1][p * 4096 + lbase]);
          gload_lds16(vg + (kv0 + 64) + vo[p], &Vs[b ^ 1][p * 4096 + lbase]);
        }
      }
      f32x4 st[4];
      __builtin_amdgcn_s_setprio(1);
#pragma unroll
      for (int j = 0; j < 4; ++j) {
        st[j] = (f32x4){0.f, 0.f, 0.f, 0.f};
        const int krow = j * 16 + lr;
#pragma unroll
        for (int c = 0; c < 4; ++c) {
          bf16x8 kf = *(const bf16x8*)&Ks[b][krow * HD_ + (((c * 64 + lhi * 16) ^ sx) >> 1)];
          st[j] = __builtin_amdgcn_mfma_f32_16x16x32_bf16(kf, qf[c], st[j], 0, 0, 0);
        }
      }
      __builtin_amdgcn_s_setprio(0);
      if (kt == ntile - 1) {
#pragma unroll
        for (int j = 0; j < 4; ++j)
#pragma unroll
          for (int r = 0; r < 4; ++r)
            st[j][r] = (kv0 + j * 16 + lhi * 4 + r <= q0 + lr) ? st[j][r] * scale2 : -3e38f;
      } else {
#pragma unroll
        for (int j = 0; j < 4; ++j)
#pragma unroll
          for (int r = 0; r < 4; ++r) st[j][r] *= scale2;
      }
      float pm = st[0][0];
#pragma unroll
      for (int j = 0; j < 4; ++j)
#pragma unroll
        for (int r = 0; r < 4; ++r) pm = fmaxf(pm, st[j][r]);
      pm = fmaxf(pm, __shfl_xor(pm, 16));
      pm = fmaxf(pm, __shfl_xor(pm, 32));
      if (!__all(pm - mrow <= 8.f)) {
        float mnew = fmaxf(mrow, pm);
        float al = __builtin_amdgcn_exp2f(mrow - mnew);
        mrow = mnew;
        lrow *= al;
        float a0 = __shfl(al, lhi * 4 + 0);
        float a1 = __shfl(al, lhi * 4 + 1);
        float a2 = __shfl(al, lhi * 4 + 2);
        float a3 = __shfl(al, lhi * 4 + 3);
#pragma unroll
        for (int dt = 0; dt < 8; ++dt) {
          accO[dt][0] *= a0; accO[dt][1] *= a1; accO[dt][2] *= a2; accO[dt][3] *= a3;
        }
      }
      float ps = 0.f;
#pragma unroll
      for (int j = 0; j < 4; ++j)
#pragma unroll
        for (int r = 0; r < 4; ++r) {
          float e = __builtin_amdgcn_exp2f(st[j][r] - mrow);
          st[j][r] = e;
          ps += e;
        }
      ps += __shfl_xor(ps, 16);
      ps += __shfl_xor(ps, 32);
      lrow += ps;
#pragma unroll
      for (int j = 0; j < 4; ++j) {
        u16x4 pw;
        pw[0] = f2bf(st[j][0]); pw[1] = f2bf(st[j][1]);
        pw[2] = f2bf(st[j][2]); pw[3] = f2bf(st[j][3]);
        *(u16x4*)&p_lds[lr * 64 + (((j * 32 + lhi * 8) ^ sx) >> 1)] = pw;
      }
      bf16x8 pa0 = *(const bf16x8*)&p_lds[lr * 64 + (((lhi * 16) ^ sx) >> 1)];
      bf16x8 pa1 = *(const bf16x8*)&p_lds[lr * 64 + (((64 + lhi * 16) ^ sx) >> 1)];
      __builtin_amdgcn_s_setprio(1);
#pragma unroll
      for (int dt = 0; dt < 8; ++dt) {
        const int vrow = dt * 16 + lr;
        bf16x8 vf0 = *(const bf16x8*)&Vs[b][vrow * 64 + (((lhi * 16) ^ sx) >> 1)];
        bf16x8 vf1 = *(const bf16x8*)&Vs[b][vrow * 64 + (((64 + lhi * 16) ^ sx) >> 1)];
        accO[dt] = __builtin_amdgcn_mfma_f32_16x16x32_bf16(pa0, vf0, accO[dt], 0, 0, 0);
        accO[dt] = __builtin_amdgcn_mfma_f32_16x16x32_bf16(pa1, vf1, accO[dt], 0, 0, 0);
      }
      __builtin_amdgcn_s_setprio(0);
      __syncthreads();
    }
    float rinv = 1.f / lrow;
    float i0 = __shfl(rinv, lhi * 4 + 0);
    float i1 = __shfl(rinv, lhi * 4 + 1);
    float i2 = __shfl(rinv, lhi * 4 + 2);
    float i3 = __shfl(rinv, lhi * 4 + 3);
    float iv[4] = {i0, i1, i2, i3};
#pragma unroll
    for (int r = 0; r < 4; ++r) {
      size_t rowoff = (size_t)(q0 + lhi * 4 + r) * (H_ * HD_) + h * HD_;
#pragma unroll
      for (int dt = 0; dt < 8; ++dt) attnb[rowoff + dt * 16 + lr] = f2bf(accO[dt][r] * iv[r]);
    }
  }
}

extern "C" void kernel_launch(void* const* d_in, const int* in_sizes, int n_in,
                              void* d_out, int out_size, void* d_ws, size_t ws_size,
                              hipStream_t stream) {
  const float* x = (const float*)d_in[0];
  // d_in[1] = mask (bool) — causal mask computed analytically, unused
  const float* cosT = (const float*)d_in[2];
  const float* sinT = (const float*)d_in[3];
  const float* Wq = (const float*)d_in[4];
  const float* Wk = (const float*)d_in[5];
  const float* Wv = (const float*)d_in[6];
  const float* Wo = (const float*)d_in[7];
  const float* qn = (const float*)d_in[8];
  const float* kn = (const float*)d_in[9];

  unsigned char* w = (unsigned char*)d_ws;
  unsigned short* xb     = (unsigned short*)(w);             // 16 MB (T,D) bf16
  unsigned short* WqkvT  = (unsigned short*)(w + 16777216);  // 48 MB (6144,4096) bf16
  unsigned short* qkvraw = (unsigned short*)(w + 67108864);  // 24 MB (T,6144) bf16
  unsigned short* qbuf   = (unsigned short*)(w + 92274688);  // 16 MB (H,T,HD)
  unsigned short* kbuf   = (unsigned short*)(w + 109051904); // 4 MB (G,T,HD)
  unsigned short* vtb    = (unsigned short*)(w + 113246208); // 4 MB (G,HD,T) -> 117.4 MB
  unsigned short* WoT    = WqkvT;  // alias: Wqkv dead after QKV GEMM (32 MB of 48)
  unsigned short* attnb  = xb;     // alias: x dead after QKV GEMM

  convert_bf16<<<dim3(4096), dim3(256), 0, stream>>>(x, xb);
  // merged Wq/Wk/Wv transpose+convert: one dispatch, 96 output row-tiles
  transpose_convert_qkv<<<dim3(64, 96), dim3(256), 0, stream>>>(Wq, Wk, Wv, WqkvT);

  // fused QKV projection: (2048,4096) x (6144,4096)^T -> (2048,6144) bf16
  gemm4<6, 0><<<dim3(16, 32), dim3(256), 0, stream>>>(xb, WqkvT, (void*)qkvraw, 2048, 6144, 4096, 4096);

  // merged q+k RMSNorm+RoPE AND V transpose: one dispatch
  post_qkv<<<dim3(20992), dim3(256), 0, stream>>>(qkvraw, qbuf, kbuf, vtb, qn, kn, cosT, sinT);
  // Wo transpose must follow the QKV GEMM (WoT aliases WqkvT)
  transpose_convert<<<dim3(64, 64), dim3(256), 0, stream>>>(Wo, WoT, 4096, 4096);

  // paired-uniform flash (R9 config): 256 identical blocks (33 tiles each)
  flash_attn<<<dim3(16, 16), dim3(512), 0, stream>>>(qbuf, kbuf, vtb, attnb);

  // Wo projection: BM=128, BN=128, 4-wave 64x64 wave tile -> grid (16,32), f32 out
  gemm4<4, 1><<<dim3(16, 32), dim3(256), 0, stream>>>(attnb, WoT, d_out, 2048, 4096, 4096, 4096);
}